// Round 2
// baseline (447.365 us; speedup 1.0000x reference)
//
#include <hip/hip_runtime.h>

typedef unsigned short u16;
typedef unsigned int   u32;
typedef __bf16 bf16x8 __attribute__((ext_vector_type(8)));
typedef float  f32x4  __attribute__((ext_vector_type(4)));

#define N_TOT 2304

__device__ __forceinline__ u16 f32_to_bf16(float f) {
  u32 u = __float_as_uint(f);
  u32 r = (u + 0x7FFFu + ((u >> 16) & 1u)) >> 16;  // RTNE
  return (u16)r;
}
__device__ __forceinline__ float bf16_to_f32(u16 h) {
  return __uint_as_float(((u32)h) << 16);
}

__device__ __forceinline__ void gload_lds16(const void* gsrc, void* lds) {
  __builtin_amdgcn_global_load_lds(
      (const __attribute__((address_space(1))) void*)gsrc,
      (__attribute__((address_space(3))) void*)lds, 16, 0, 0);
}

// ---------- kernel 1: per-task Frobenius sum-of-squares ----------
__global__ void norms_kernel(const float* __restrict__ Aq, const float* __restrict__ Bq,
                             const float* __restrict__ Av, const float* __restrict__ Bv,
                             float* __restrict__ sumsq) {
  int b = blockIdx.x;  // 0..39 : which*10 + t
  int which = b / 10, t = b % 10;
  const float* src =
      (which == 0 ? Aq : which == 1 ? Bq : which == 2 ? Av : Bv) + t * 12288;
  float s = 0.f;
  for (int i = threadIdx.x; i < 12288; i += 256) { float v = src[i]; s += v * v; }
  for (int off = 32; off > 0; off >>= 1) s += __shfl_down(s, off, 64);
  __shared__ float red[4];
  if ((threadIdx.x & 63) == 0) red[threadIdx.x >> 6] = s;
  __syncthreads();
  if (threadIdx.x == 0) sumsq[b] = red[0] + red[1] + red[2] + red[3];
}

// ---------- kernel 2: softmax gate -> folded per-task weights wq/wv ----------
__global__ void weights_kernel(const float* __restrict__ logits, const float* __restrict__ alpha,
                               const float* __restrict__ sumsq,
                               float* __restrict__ wq, float* __restrict__ wv) {
  int t = threadIdx.x;
  if (t >= 10) return;
  float m = -1e30f;
  for (int i = 0; i < 10; ++i) m = fmaxf(m, logits[i]);
  float sum = 0.f;
  for (int i = 0; i < 10; ++i) sum += expf(logits[i] - m);   // TAU = 1.0
  float coef = (expf(logits[t] - m) / sum) * alpha[t];
  wq[t] = coef / (sqrtf(sumsq[t])      * sqrtf(sumsq[10 + t]) + 1e-8f);
  wv[t] = coef / (sqrtf(sumsq[20 + t]) * sqrtf(sumsq[30 + t]) + 1e-8f);
}

// ---------- kernel 3: build W_eff[n][k] = qkv_w + LoRA delta, split bf16 hi/lo ----------
__global__ __launch_bounds__(256) void build_weff(
    const float* __restrict__ qkv_w,
    const float* __restrict__ Aq, const float* __restrict__ Bq,
    const float* __restrict__ Av, const float* __restrict__ Bv,
    const float* __restrict__ wq, const float* __restrict__ wv,
    u16* __restrict__ Whi, u16* __restrict__ Wlo) {
  __shared__ float As[160][64];
  __shared__ float Bs[160][32];
  __shared__ float wsh[16];

  const int k0 = blockIdx.x * 64;
  const int n0 = blockIdx.y * 32;
  const int tid = threadIdx.x;
  const int nl = tid >> 3;
  const int kg = tid & 7;

  float acc[8] = {0, 0, 0, 0, 0, 0, 0, 0};
  const bool is_q = (n0 < 768);
  const bool is_v = (n0 >= 1536);
  if (is_q || is_v) {
    const float* A  = is_q ? Aq : Av;
    const float* Bm = is_q ? Bq : Bv;
    const float* w  = is_q ? wq : wv;
    const int noff = is_q ? n0 : (n0 - 1536);
    for (int i = tid; i < 10240; i += 256)
      As[i >> 6][i & 63] = A[(i >> 6) * 768 + k0 + (i & 63)];
    for (int i = tid; i < 5120; i += 256) {
      int tr = i >> 5, n = i & 31;
      Bs[tr][n] = Bm[(tr >> 4) * 12288 + (noff + n) * 16 + (tr & 15)];
    }
    if (tid < 10) wsh[tid] = w[tid];
    __syncthreads();
    for (int tr = 0; tr < 160; ++tr) {
      float wb = wsh[tr >> 4] * Bs[tr][nl];
#pragma unroll
      for (int j = 0; j < 8; ++j) acc[j] += wb * As[tr][kg * 8 + j];
    }
  }
  const int n = n0 + nl;
  const size_t base = (size_t)n * 768 + k0 + kg * 8;
#pragma unroll
  for (int j = 0; j < 8; ++j) {
    float v = qkv_w[base + j] + acc[j];
    u16 h = f32_to_bf16(v);
    u16 l = f32_to_bf16(v - bf16_to_f32(h));
    Whi[base + j] = h;
    Wlo[base + j] = l;
  }
}

// ---------- kernel 4: split x into bf16 hi/lo ----------
__global__ void split_x(const float* __restrict__ x, u16* __restrict__ Xhi, u16* __restrict__ Xlo) {
  int i4 = blockIdx.x * 256 + threadIdx.x;
  if (i4 >= 3145728) return;
  float4 v = ((const float4*)x)[i4];
  u32 h0 = f32_to_bf16(v.x), h1 = f32_to_bf16(v.y), h2 = f32_to_bf16(v.z), h3 = f32_to_bf16(v.w);
  u32 l0 = f32_to_bf16(v.x - bf16_to_f32((u16)h0));
  u32 l1 = f32_to_bf16(v.y - bf16_to_f32((u16)h1));
  u32 l2 = f32_to_bf16(v.z - bf16_to_f32((u16)h2));
  u32 l3 = f32_to_bf16(v.w - bf16_to_f32((u16)h3));
  ((uint2*)Xhi)[i4] = make_uint2(h0 | (h1 << 16), h2 | (h3 << 16));
  ((uint2*)Xlo)[i4] = make_uint2(l0 | (l1 << 16), l2 | (l3 << 16));
}

// ---------- kernel 5: K-concat split GEMM, counted-vmcnt pipeline ----------
// out[16384,2304] = Xcat[16384,2304k] @ Wcat[2304,2304k]^T + bias, where
// k-region 0: xhi*whi, 1: xhi*wlo, 2: xlo*whi  (== 3-product bf16 split).
// BM=BN=256, BK=32, 8 waves(2Mx4N), 4-deep LDS rotation (4 x 32KB = 128KB dyn).
// Phase t: ds_read frags(buf t&3) | stage tile t+2 (4 gload_lds) | vmcnt(4) |
//          s_barrier | setprio(1) 32xMFMA setprio(0).
// Tile t's staging drained by phase t-1's vmcnt(4)+barrier (uniform across waves).
// LDS swizzle: logical (row R, 16B-slot S) at phys unit P=(R>>1)*8+((S+4*(R&1))^((R>>1)&7))
//   -> each b128 wave-read lands 2 lanes per bank-quad = conflict-free.
//   Staging keeps LDS linear; the *global source* is inverse-swizzled (rule 21).
__global__ __launch_bounds__(512, 2) void gemm_kc(
    const u16* __restrict__ Xhi, const u16* __restrict__ Xlo,
    const u16* __restrict__ Whi, const u16* __restrict__ Wlo,
    const float* __restrict__ bias, float* __restrict__ out) {
  extern __shared__ char smem[];  // 131072 bytes

  const int tid  = threadIdx.x;
  const int lane = tid & 63;
  const int wid  = tid >> 6;

  // T1: bijective XCD swizzle (576 % 8 == 0), n-inner for X L2 reuse
  const int bid = blockIdx.x;
  const int swz = (bid & 7) * 72 + (bid >> 3);
  const int m0 = (swz / 9) << 8;
  const int n0 = (swz % 9) << 8;

  const int wm = (wid >> 2) << 7;   // 0 / 128
  const int wn = (wid & 3) << 6;    // 0 / 64 / 128 / 192
  const int fl = lane & 15, fs = lane >> 4;

  // fragment LDS byte offsets (within one 16KB tile)
  int aFrag[8], bFrag[4];
#pragma unroll
  for (int i = 0; i < 8; ++i) {
    int R = wm + i * 16 + fl;
    int pr = R >> 1;
    int u = (fs + ((R & 1) << 2)) ^ (pr & 7);
    aFrag[i] = (pr * 8 + u) * 16;
  }
#pragma unroll
  for (int j = 0; j < 4; ++j) {
    int R = wn + j * 16 + fl;
    int pr = R >> 1;
    int u = (fs + ((R & 1) << 2)) ^ (pr & 7);
    bFrag[j] = (pr * 8 + u) * 16;
  }

  // staging precompute: thread's 2 A-loads + 2 B-loads per tile.
  // phys unit P -> logical (r,s): u=p^(pr&7); r=2*pr+(u>>2); s=u&3
  int ldsByte[2];
  long aSrcOff[2], bSrcOff[2];   // element offsets excl. ksrc
#pragma unroll
  for (int jj = 0; jj < 2; ++jj) {
    int P = jj * 512 + tid;
    int pr = P >> 3, p = P & 7;
    int u = p ^ (pr & 7);
    int r = (pr << 1) | (u >> 2);
    int s = u & 3;
    ldsByte[jj]  = P * 16;
    aSrcOff[jj] = (long)(m0 + r) * 768 + s * 8;
    bSrcOff[jj] = (long)(n0 + r) * 768 + s * 8;
  }

  auto stage = [&](int t2, int bufi) {
    int tc = t2 > 71 ? 71 : t2;
    int reg = tc / 24;
    int ksrc = (tc - reg * 24) << 5;
    const u16* xb = (reg == 2) ? Xlo : Xhi;
    const u16* wb = (reg == 1) ? Wlo : Whi;
    char* base = smem + bufi * 32768;
    gload_lds16(xb + aSrcOff[0] + ksrc, base + ldsByte[0]);
    gload_lds16(xb + aSrcOff[1] + ksrc, base + ldsByte[1]);
    gload_lds16(wb + bSrcOff[0] + ksrc, base + 16384 + ldsByte[0]);
    gload_lds16(wb + bSrcOff[1] + ksrc, base + 16384 + ldsByte[1]);
  };

  f32x4 acc[8][4] = {};

  stage(0, 0);
  stage(1, 1);
  asm volatile("s_waitcnt vmcnt(4)" ::: "memory");   // tile 0 drained; tile 1 in flight
  __builtin_amdgcn_sched_barrier(0);
  __builtin_amdgcn_s_barrier();

  for (int t = 0; t < 72; ++t) {
    char* bufA = smem + (t & 3) * 32768;
    char* bufB = bufA + 16384;
    bf16x8 a[8], b[4];
#pragma unroll
    for (int i = 0; i < 8; ++i) a[i] = *(const bf16x8*)(bufA + aFrag[i]);
#pragma unroll
    for (int j = 0; j < 4; ++j) b[j] = *(const bf16x8*)(bufB + bFrag[j]);

    stage(t + 2, (t + 2) & 3);                       // overwrites tile t-2 (2 barriers old)
    asm volatile("s_waitcnt vmcnt(4)" ::: "memory"); // tile t+1 drained; t+2 in flight
    __builtin_amdgcn_sched_barrier(0);
    __builtin_amdgcn_s_barrier();

    __builtin_amdgcn_s_setprio(1);
#pragma unroll
    for (int i = 0; i < 8; ++i)
#pragma unroll
      for (int j = 0; j < 4; ++j)
        acc[i][j] = __builtin_amdgcn_mfma_f32_16x16x32_bf16(a[i], b[j], acc[i][j], 0, 0, 0);
    __builtin_amdgcn_s_setprio(0);
  }

  // epilogue: C/D layout col=lane&15, row=(lane>>4)*4+reg [HW-verified]
#pragma unroll
  for (int j = 0; j < 4; ++j) {
    const int n = n0 + wn + j * 16 + fl;
    const float bj = bias[n];
#pragma unroll
    for (int i = 0; i < 8; ++i) {
      const int mbase = m0 + wm + i * 16 + (fs << 2);
#pragma unroll
      for (int r = 0; r < 4; ++r)
        out[(size_t)(mbase + r) * N_TOT + n] = acc[i][j][r] + bj;
    }
  }
}

extern "C" void kernel_launch(void* const* d_in, const int* in_sizes, int n_in,
                              void* d_out, int out_size, void* d_ws, size_t ws_size,
                              hipStream_t stream) {
  const float* x     = (const float*)d_in[0];
  const float* Aq    = (const float*)d_in[1];
  const float* Bq    = (const float*)d_in[2];
  const float* Av    = (const float*)d_in[3];
  const float* Bv    = (const float*)d_in[4];
  const float* qkvw  = (const float*)d_in[5];
  const float* qkvb  = (const float*)d_in[6];
  const float* gate  = (const float*)d_in[7];
  const float* alpha = (const float*)d_in[8];
  float* out = (float*)d_out;

  char* ws = (char*)d_ws;
  float* sumsq = (float*)ws;
  float* wq    = (float*)(ws + 256);
  float* wv    = (float*)(ws + 512);
  u16* Whi = (u16*)(ws + 1024);
  u16* Wlo = Whi + 1769472;
  u16* Xhi = Wlo + 1769472;
  u16* Xlo = Xhi + 12582912;

  static bool attr_set = false;
  if (!attr_set) {
    hipFuncSetAttribute((const void*)gemm_kc,
                        hipFuncAttributeMaxDynamicSharedMemorySize, 131072);
    attr_set = true;
  }

  hipLaunchKernelGGL(norms_kernel,   dim3(40),     dim3(256), 0, stream, Aq, Bq, Av, Bv, sumsq);
  hipLaunchKernelGGL(weights_kernel, dim3(1),      dim3(64),  0, stream, gate, alpha, sumsq, wq, wv);
  hipLaunchKernelGGL(build_weff,     dim3(12, 72), dim3(256), 0, stream, qkvw, Aq, Bq, Av, Bv, wq, wv, Whi, Wlo);
  hipLaunchKernelGGL(split_x,        dim3(12288),  dim3(256), 0, stream, x, Xhi, Xlo);
  hipLaunchKernelGGL(gemm_kc,        dim3(576),    dim3(512), 131072, stream,
                     Xhi, Xlo, Whi, Wlo, qkvb, out);
}